// Round 2
// baseline (692.074 us; speedup 1.0000x reference)
//
#include <hip/hip_runtime.h>
#include <hip/hip_bf16.h>
#include <stdint.h>

// Problem constants (from reference)
#define N_NODES  4096
#define EMB_DIM  512
#define N_HEADS  8
#define K_SPARSE 128
#define HEAD_DIM 64   // EMB_DIM / N_HEADS

typedef __attribute__((ext_vector_type(8))) __bf16 bf16x8;
typedef __attribute__((ext_vector_type(4))) float  f32x4;

__device__ __forceinline__ float bf2f(unsigned short u) {
    union { unsigned int i; float f; } v;
    v.i = ((unsigned int)u) << 16;
    return v.f;
}

__device__ __forceinline__ unsigned short f2bf(float f) {
    // round-to-nearest-even fp32 -> bf16
    union { float f; unsigned int i; } v;
    v.f = f;
    unsigned int x = v.i;
    unsigned int rounding = 0x7fffu + ((x >> 16) & 1u);
    x += rounding;
    return (unsigned short)(x >> 16);
}

// ---------------------------------------------------------------------------
// Kernel 1: fused Q/K projection GEMM, fp32 inputs -> bf16 outputs.
//   C[m, n] = sum_k X[m,k] * W[n,k] + bias[n]   (X @ W^T + b)
// Tile: 64x128, BK=32, 256 threads = 4 waves (2x2), each wave 32x64 via
// 2x4 grid of 16x16x32 bf16 MFMAs. Grid = 64 x 4 x 2 = 512 blocks.
// (unchanged from verified version)
// ---------------------------------------------------------------------------
__global__ __launch_bounds__(256) void proj_kernel(
    const float* __restrict__ X,
    const float* __restrict__ Wq, const float* __restrict__ bq,
    const float* __restrict__ Wk, const float* __restrict__ bk,
    unsigned short* __restrict__ Qb, unsigned short* __restrict__ Kb)
{
    __shared__ unsigned short As[64][40];    // 64 rows x 32 bf16 (+pad)
    __shared__ unsigned short Bs[128][40];   // 128 rows x 32 bf16 (+pad)

    const float* __restrict__ W    = blockIdx.z ? Wk : Wq;
    const float* __restrict__ bias = blockIdx.z ? bk : bq;
    unsigned short* __restrict__ out = blockIdx.z ? Kb : Qb;

    const int t    = threadIdx.x;
    const int M0   = blockIdx.x * 64;
    const int N0   = blockIdx.y * 128;
    const int lane = t & 63;
    const int wave = t >> 6;
    const int wm   = (wave >> 1) * 32;   // wave row offset (0 or 32)
    const int wn   = (wave & 1) * 64;    // wave col offset (0 or 64)

    const int arow = t >> 2;
    const int acol = (t & 3) * 8;
    const int brow = t >> 1;
    const int bcol = (t & 1) * 16;

    f32x4 acc[2][4] = {};

    for (int kt = 0; kt < EMB_DIM / 32; ++kt) {
        const int k0 = kt * 32;
        {
            const float4* srcA = (const float4*)(X + (size_t)(M0 + arow) * EMB_DIM + k0 + acol);
            float4 va0 = srcA[0], va1 = srcA[1];
            unsigned int pa[4];
            pa[0] = (unsigned int)f2bf(va0.x) | ((unsigned int)f2bf(va0.y) << 16);
            pa[1] = (unsigned int)f2bf(va0.z) | ((unsigned int)f2bf(va0.w) << 16);
            pa[2] = (unsigned int)f2bf(va1.x) | ((unsigned int)f2bf(va1.y) << 16);
            pa[3] = (unsigned int)f2bf(va1.z) | ((unsigned int)f2bf(va1.w) << 16);
            *(uint4*)&As[arow][acol] = make_uint4(pa[0], pa[1], pa[2], pa[3]);

            const float4* srcB = (const float4*)(W + (size_t)(N0 + brow) * EMB_DIM + k0 + bcol);
            unsigned int pb[8];
            #pragma unroll
            for (int c = 0; c < 4; ++c) {
                float4 vb = srcB[c];
                pb[c * 2 + 0] = (unsigned int)f2bf(vb.x) | ((unsigned int)f2bf(vb.y) << 16);
                pb[c * 2 + 1] = (unsigned int)f2bf(vb.z) | ((unsigned int)f2bf(vb.w) << 16);
            }
            uint4* dstB = (uint4*)&Bs[brow][bcol];
            dstB[0] = make_uint4(pb[0], pb[1], pb[2], pb[3]);
            dstB[1] = make_uint4(pb[4], pb[5], pb[6], pb[7]);
        }
        __syncthreads();

        bf16x8 af[2], bff[4];
        #pragma unroll
        for (int i = 0; i < 2; ++i)
            af[i] = __builtin_bit_cast(bf16x8,
                *(const uint4*)&As[wm + i * 16 + (lane & 15)][(lane >> 4) * 8]);
        #pragma unroll
        for (int i = 0; i < 4; ++i)
            bff[i] = __builtin_bit_cast(bf16x8,
                *(const uint4*)&Bs[wn + i * 16 + (lane & 15)][(lane >> 4) * 8]);

        #pragma unroll
        for (int mi = 0; mi < 2; ++mi)
            #pragma unroll
            for (int ni = 0; ni < 4; ++ni)
                acc[mi][ni] = __builtin_amdgcn_mfma_f32_16x16x32_bf16(
                    af[mi], bff[ni], acc[mi][ni], 0, 0, 0);
        __syncthreads();
    }

    // epilogue: +bias, fp32 -> bf16. C/D map: col=lane&15, row=(lane>>4)*4+r
    #pragma unroll
    for (int mi = 0; mi < 2; ++mi) {
        #pragma unroll
        for (int ni = 0; ni < 4; ++ni) {
            const int col = N0 + wn + ni * 16 + (lane & 15);
            const float bval = bias[col];
            #pragma unroll
            for (int r = 0; r < 4; ++r) {
                const int row = M0 + wm + mi * 16 + (lane >> 4) * 4 + r;
                out[(size_t)row * EMB_DIM + col] = f2bf(acc[mi][ni][r] + bval);
            }
        }
    }
}

// ---------------------------------------------------------------------------
// Kernel 2 (fused, direct-store): one block per output row (h, n).
//
// Restructure vs previous fused version: the 16 KB output row is NOT built
// in LDS. Plain (cache-allocating) zero stores are issued straight from
// registers at block start -- zero dependencies, so the store pipe fills
// immediately (fill-kernel behavior, ~6.2 TB/s precedent). The gather/dot/
// ticket work runs while those stores drain. Finally only the <=128 score
// dwords are scattered directly to global; the target lines were just
// zero-written so they are L2-resident, and __syncthreads()'s implicit
// vmcnt(0)-before-s_barrier drain guarantees every wave's zeros land before
// any score store (same-address WAW resolved by L2 arrival order).
//
// LDS keeps only the 4096-entry ticket array (last-write-wins dedup via
// atomicMax, same proven logic) + the 128 indices. 2 barriers instead of 4,
// no 16 KB LDS readback on the store path.
// ---------------------------------------------------------------------------
__global__ __launch_bounds__(256) void scatter_kernel(
    const unsigned short* __restrict__ Qb,
    const unsigned short* __restrict__ Kb,
    const int* __restrict__ sidx,
    float* __restrict__ out)
{
    __shared__ unsigned int tags[N_NODES];   // 16 KB ticket array
    __shared__ int sIdx[K_SPARSE];

    const int t = threadIdx.x;
    const int b = blockIdx.x;
    const int h = b >> 12;
    const int n = b & (N_NODES - 1);
    const int j = t & 7;            // sector lane within key group

    // ---- phase 0: issue the full 16 KB row of zero stores immediately ----
    float* orow = out + (size_t)b * N_NODES;
    f32x4* orowv = (f32x4*)orow;
    const f32x4 z4 = {0.0f, 0.0f, 0.0f, 0.0f};
    #pragma unroll
    for (int i = 0; i < 4; ++i) orowv[t + 256 * i] = z4;

    // ---- issue independent global loads ----
    // Q slice: 8 bf16 (16 B) this lane needs, broadcast across each 8-lane group
    const uint4 qu = *(const uint4*)(Qb + (size_t)n * EMB_DIM + h * HEAD_DIM + j * 8);
    int myIdxLd = 0;
    if (t < K_SPARSE)
        myIdxLd = sidx[((size_t)b) * K_SPARSE + t];

    // ---- zero the ticket array (256 threads x 4 uint4 = 4096 uints) ----
    uint4* tagv = (uint4*)tags;
    const uint4 zu = make_uint4(0u, 0u, 0u, 0u);
    #pragma unroll
    for (int i = 0; i < 4; ++i) tagv[t + 256 * i] = zu;

    if (t < K_SPARSE) sIdx[t] = myIdxLd;

    // unpack this lane's 8 Q values
    float q[8];
    {
        unsigned int uu[4] = {qu.x, qu.y, qu.z, qu.w};
        #pragma unroll
        for (int w = 0; w < 4; ++w) {
            q[2 * w + 0] = bf2f((unsigned short)(uu[w] & 0xffffu));
            q[2 * w + 1] = bf2f((unsigned short)(uu[w] >> 16));
        }
    }
    __syncthreads();

    // ticket race: one thread per key (register idx, no LDS re-read);
    // max ticket = last occurrence wins (matches scatter_ semantics)
    if (t < K_SPARSE) atomicMax(&tags[myIdxLd], (unsigned int)(t + 1));

    // sectored gather + dot: key kk = (t>>3) + 32*iter, lane j covers 8 dims
    float score[4];
    int   kidx[4];
    #pragma unroll
    for (int iter = 0; iter < 4; ++iter) {
        const int kk  = (t >> 3) + 32 * iter;
        const int idx = sIdx[kk];
        kidx[iter] = idx;
        const uint4 u = *(const uint4*)(Kb + (size_t)idx * EMB_DIM + h * HEAD_DIM + j * 8);
        unsigned int uu[4] = {u.x, u.y, u.z, u.w};
        float acc = 0.0f;
        #pragma unroll
        for (int w = 0; w < 4; ++w) {
            acc += bf2f((unsigned short)(uu[w] & 0xffffu)) * q[2 * w + 0];
            acc += bf2f((unsigned short)(uu[w] >> 16))     * q[2 * w + 1];
        }
        // reduce across the 8-lane group
        acc += __shfl_xor(acc, 1);
        acc += __shfl_xor(acc, 2);
        acc += __shfl_xor(acc, 4);
        score[iter] = acc * 0.125f;   // 1/sqrt(64)
    }

    // Barrier: (a) all atomicMax tickets visible; (b) implicit
    // vmcnt(0)-before-s_barrier drains every wave's zero stores, so the
    // score stores below land strictly after the zeros (same L2 bank per
    // address => arrival order wins).
    __syncthreads();

    #pragma unroll
    for (int iter = 0; iter < 4; ++iter) {
        const int kk = (t >> 3) + 32 * iter;
        if (j == 0 && tags[kidx[iter]] == (unsigned int)(kk + 1))
            orow[kidx[iter]] = score[iter];
    }
}

extern "C" void kernel_launch(void* const* d_in, const int* in_sizes, int n_in,
                              void* d_out, int out_size, void* d_ws, size_t ws_size,
                              hipStream_t stream) {
    const float* emb = (const float*)d_in[0];
    const float* Wq  = (const float*)d_in[1];
    const float* bq  = (const float*)d_in[2];
    const float* Wk  = (const float*)d_in[3];
    const float* bk  = (const float*)d_in[4];
    const int*   si  = (const int*)d_in[5];
    float* out = (float*)d_out;

    // workspace: Qb (4 MB) + Kb (4 MB) bf16
    unsigned short* Qb = (unsigned short*)d_ws;
    unsigned short* Kb = Qb + (size_t)N_NODES * EMB_DIM;

    dim3 pg(N_NODES / 64, EMB_DIM / 128, 2);   // 64 x 4 x 2 = 512 blocks
    proj_kernel<<<pg, 256, 0, stream>>>(emb, Wq, bq, Wk, bk, Qb, Kb);

    scatter_kernel<<<N_HEADS * N_NODES, 256, 0, stream>>>(Qb, Kb, si, out);
}

// Round 3
// 579.594 us; speedup vs baseline: 1.1941x; 1.1941x over previous
//
#include <hip/hip_runtime.h>
#include <hip/hip_bf16.h>
#include <stdint.h>

// Problem constants (from reference)
#define N_NODES  4096
#define EMB_DIM  512
#define N_HEADS  8
#define K_SPARSE 128
#define HEAD_DIM 64   // EMB_DIM / N_HEADS

typedef __attribute__((ext_vector_type(8))) __bf16 bf16x8;
typedef __attribute__((ext_vector_type(4))) float  f32x4;

__device__ __forceinline__ float bf2f(unsigned short u) {
    union { unsigned int i; float f; } v;
    v.i = ((unsigned int)u) << 16;
    return v.f;
}

__device__ __forceinline__ unsigned short f2bf(float f) {
    // round-to-nearest-even fp32 -> bf16
    union { float f; unsigned int i; } v;
    v.f = f;
    unsigned int x = v.i;
    unsigned int rounding = 0x7fffu + ((x >> 16) & 1u);
    x += rounding;
    return (unsigned short)(x >> 16);
}

// ---------------------------------------------------------------------------
// Kernel 1: fused Q/K projection GEMM, fp32 inputs -> bf16 outputs.
//   C[m, n] = sum_k X[m,k] * W[n,k] + bias[n]   (X @ W^T + b)
// Tile: 64x128, BK=32, 256 threads = 4 waves (2x2), each wave 32x64 via
// 2x4 grid of 16x16x32 bf16 MFMAs. Grid = 64 x 4 x 2 = 512 blocks.
// (unchanged from verified version)
// ---------------------------------------------------------------------------
__global__ __launch_bounds__(256) void proj_kernel(
    const float* __restrict__ X,
    const float* __restrict__ Wq, const float* __restrict__ bq,
    const float* __restrict__ Wk, const float* __restrict__ bk,
    unsigned short* __restrict__ Qb, unsigned short* __restrict__ Kb)
{
    __shared__ unsigned short As[64][40];    // 64 rows x 32 bf16 (+pad)
    __shared__ unsigned short Bs[128][40];   // 128 rows x 32 bf16 (+pad)

    const float* __restrict__ W    = blockIdx.z ? Wk : Wq;
    const float* __restrict__ bias = blockIdx.z ? bk : bq;
    unsigned short* __restrict__ out = blockIdx.z ? Kb : Qb;

    const int t    = threadIdx.x;
    const int M0   = blockIdx.x * 64;
    const int N0   = blockIdx.y * 128;
    const int lane = t & 63;
    const int wave = t >> 6;
    const int wm   = (wave >> 1) * 32;   // wave row offset (0 or 32)
    const int wn   = (wave & 1) * 64;    // wave col offset (0 or 64)

    const int arow = t >> 2;
    const int acol = (t & 3) * 8;
    const int brow = t >> 1;
    const int bcol = (t & 1) * 16;

    f32x4 acc[2][4] = {};

    for (int kt = 0; kt < EMB_DIM / 32; ++kt) {
        const int k0 = kt * 32;
        {
            const float4* srcA = (const float4*)(X + (size_t)(M0 + arow) * EMB_DIM + k0 + acol);
            float4 va0 = srcA[0], va1 = srcA[1];
            unsigned int pa[4];
            pa[0] = (unsigned int)f2bf(va0.x) | ((unsigned int)f2bf(va0.y) << 16);
            pa[1] = (unsigned int)f2bf(va0.z) | ((unsigned int)f2bf(va0.w) << 16);
            pa[2] = (unsigned int)f2bf(va1.x) | ((unsigned int)f2bf(va1.y) << 16);
            pa[3] = (unsigned int)f2bf(va1.z) | ((unsigned int)f2bf(va1.w) << 16);
            *(uint4*)&As[arow][acol] = make_uint4(pa[0], pa[1], pa[2], pa[3]);

            const float4* srcB = (const float4*)(W + (size_t)(N0 + brow) * EMB_DIM + k0 + bcol);
            unsigned int pb[8];
            #pragma unroll
            for (int c = 0; c < 4; ++c) {
                float4 vb = srcB[c];
                pb[c * 2 + 0] = (unsigned int)f2bf(vb.x) | ((unsigned int)f2bf(vb.y) << 16);
                pb[c * 2 + 1] = (unsigned int)f2bf(vb.z) | ((unsigned int)f2bf(vb.w) << 16);
            }
            uint4* dstB = (uint4*)&Bs[brow][bcol];
            dstB[0] = make_uint4(pb[0], pb[1], pb[2], pb[3]);
            dstB[1] = make_uint4(pb[4], pb[5], pb[6], pb[7]);
        }
        __syncthreads();

        bf16x8 af[2], bff[4];
        #pragma unroll
        for (int i = 0; i < 2; ++i)
            af[i] = __builtin_bit_cast(bf16x8,
                *(const uint4*)&As[wm + i * 16 + (lane & 15)][(lane >> 4) * 8]);
        #pragma unroll
        for (int i = 0; i < 4; ++i)
            bff[i] = __builtin_bit_cast(bf16x8,
                *(const uint4*)&Bs[wn + i * 16 + (lane & 15)][(lane >> 4) * 8]);

        #pragma unroll
        for (int mi = 0; mi < 2; ++mi)
            #pragma unroll
            for (int ni = 0; ni < 4; ++ni)
                acc[mi][ni] = __builtin_amdgcn_mfma_f32_16x16x32_bf16(
                    af[mi], bff[ni], acc[mi][ni], 0, 0, 0);
        __syncthreads();
    }

    // epilogue: +bias, fp32 -> bf16. C/D map: col=lane&15, row=(lane>>4)*4+r
    #pragma unroll
    for (int mi = 0; mi < 2; ++mi) {
        #pragma unroll
        for (int ni = 0; ni < 4; ++ni) {
            const int col = N0 + wn + ni * 16 + (lane & 15);
            const float bval = bias[col];
            #pragma unroll
            for (int r = 0; r < 4; ++r) {
                const int row = M0 + wm + mi * 16 + (lane >> 4) * 4 + r;
                out[(size_t)row * EMB_DIM + col] = f2bf(acc[mi][ni][r] + bval);
            }
        }
    }
}

// ---------------------------------------------------------------------------
// Kernel 2: wave-autonomous scatter. ONE 64-lane wave per output row (h, n).
// ZERO barriers: all ordering is intra-wave (in-order LDS pipe + lgkmcnt
// waits), indices distributed by __shfl instead of an LDS sIdx array.
//
//  - lane t holds keys t and t+64 (tickets t+1 / t+65; atomicMax dedup,
//    last occurrence wins, same proven logic as the 559 us baseline)
//  - gather: 16 passes, 8 lanes per key (lane j = t&7 covers bytes
//    [16j,16j+16) of the key's 128 B head-slice), 3x shfl_xor reduce
//  - row built in 16 KB LDS (aliased as ticket array), streamed out with
//    nontemporal f32x4 stores (NT = no L2 allocate, keeps the 4 MB Kb
//    table L2-resident for the gather -- round-2 plain stores proved the
//    pollution costs ~130 us)
//  - LDS exactly 16 KB/block -> 10 independent blocks/CU, each at its own
//    phase -> steady NT-store feed instead of barrier-locked bursts
// ---------------------------------------------------------------------------
__global__ __launch_bounds__(64) void scatter_kernel(
    const unsigned short* __restrict__ Qb,
    const unsigned short* __restrict__ Kb,
    const int* __restrict__ sidx,
    float* __restrict__ out)
{
    __shared__ float rowbuf[N_NODES];   // 16 KB; aliased as uint tickets

    const int t = threadIdx.x;          // 0..63
    const int b = blockIdx.x;
    const int h = b >> 12;
    const int n = b & (N_NODES - 1);
    const int j = t & 7;                // sector lane within 8-lane key group
    const int g = t >> 3;               // key group 0..7

    // ---- issue independent global loads first ----
    const int myIdx0 = sidx[(size_t)b * K_SPARSE + t];        // key t
    const int myIdx1 = sidx[(size_t)b * K_SPARSE + 64 + t];   // key t+64
    const uint4 qu = *(const uint4*)(Qb + (size_t)n * EMB_DIM + h * HEAD_DIM + j * 8);

    // ---- zero rowbuf / ticket array: 64 lanes x 16 f32x4 = 4096 floats ----
    f32x4* rowv = (f32x4*)rowbuf;
    const f32x4 z4 = {0.0f, 0.0f, 0.0f, 0.0f};
    #pragma unroll
    for (int i = 0; i < 16; ++i) rowv[t + 64 * i] = z4;

    // unpack this lane's 8 Q values
    float q[8];
    {
        unsigned int uu[4] = {qu.x, qu.y, qu.z, qu.w};
        #pragma unroll
        for (int w = 0; w < 4; ++w) {
            q[2 * w + 0] = bf2f((unsigned short)(uu[w] & 0xffffu));
            q[2 * w + 1] = bf2f((unsigned short)(uu[w] >> 16));
        }
    }

    // ---- ticket race (zeros complete first: in-order DS pipe + waitcnt) ----
    unsigned int* tags = (unsigned int*)rowbuf;
    asm volatile("s_waitcnt lgkmcnt(0)" ::: "memory");
    atomicMax(&tags[myIdx0], (unsigned int)(t + 1));
    atomicMax(&tags[myIdx1], (unsigned int)(t + 65));

    // ---- sectored gather + dot: 16 passes x 8 keys; idx via shfl ----
    float score[16];
    int   kidx[16];
    #pragma unroll
    for (int p = 0; p < 16; ++p) {
        const int kk  = g + 8 * p;
        const int idx = (p < 8) ? __shfl(myIdx0, kk) : __shfl(myIdx1, kk - 64);
        kidx[p] = idx;
        const uint4 u = *(const uint4*)(Kb + (size_t)idx * EMB_DIM + h * HEAD_DIM + j * 8);
        unsigned int uu[4] = {u.x, u.y, u.z, u.w};
        float acc = 0.0f;
        #pragma unroll
        for (int w = 0; w < 4; ++w) {
            acc += bf2f((unsigned short)(uu[w] & 0xffffu)) * q[2 * w + 0];
            acc += bf2f((unsigned short)(uu[w] >> 16))     * q[2 * w + 1];
        }
        acc += __shfl_xor(acc, 1);
        acc += __shfl_xor(acc, 2);
        acc += __shfl_xor(acc, 4);
        score[p] = acc * 0.125f;   // 1/sqrt(64)
    }

    // ---- dedup win-check then scatter into rowbuf (j==0 lane per group) ----
    // All this wave's atomics are our own: lgkmcnt(0) makes tickets final.
    asm volatile("s_waitcnt lgkmcnt(0)" ::: "memory");
    if (j == 0) {
        unsigned int winmask = 0;
        #pragma unroll
        for (int p = 0; p < 16; ++p)
            if (tags[kidx[p]] == (unsigned int)(g + 8 * p + 1)) winmask |= (1u << p);
        // program order within the wave: all tag reads above issue before the
        // float overwrites below (in-order DS pipe); waitcnt for safety
        asm volatile("s_waitcnt lgkmcnt(0)" ::: "memory");
        #pragma unroll
        for (int p = 0; p < 16; ++p)
            if (winmask & (1u << p)) rowbuf[kidx[p]] = score[p];
    }
    asm volatile("s_waitcnt lgkmcnt(0)" ::: "memory");

    // ---- coalesced nontemporal row write: 16 KB ----
    f32x4* orowv = (f32x4*)(out + (size_t)b * N_NODES);
    #pragma unroll
    for (int i = 0; i < 16; ++i) {
        f32x4 v = rowv[t + 64 * i];
        __builtin_nontemporal_store(v, &orowv[t + 64 * i]);
    }
}

extern "C" void kernel_launch(void* const* d_in, const int* in_sizes, int n_in,
                              void* d_out, int out_size, void* d_ws, size_t ws_size,
                              hipStream_t stream) {
    const float* emb = (const float*)d_in[0];
    const float* Wq  = (const float*)d_in[1];
    const float* bq  = (const float*)d_in[2];
    const float* Wk  = (const float*)d_in[3];
    const float* bk  = (const float*)d_in[4];
    const int*   si  = (const int*)d_in[5];
    float* out = (float*)d_out;

    // workspace: Qb (4 MB) + Kb (4 MB) bf16
    unsigned short* Qb = (unsigned short*)d_ws;
    unsigned short* Kb = Qb + (size_t)N_NODES * EMB_DIM;

    dim3 pg(N_NODES / 64, EMB_DIM / 128, 2);   // 64 x 4 x 2 = 512 blocks
    proj_kernel<<<pg, 256, 0, stream>>>(emb, Wq, bq, Wk, bk, Qb, Kb);

    scatter_kernel<<<N_HEADS * N_NODES, 64, 0, stream>>>(Qb, Kb, si, out);
}

// Round 4
// 563.866 us; speedup vs baseline: 1.2274x; 1.0279x over previous
//
#include <hip/hip_runtime.h>
#include <hip/hip_bf16.h>
#include <stdint.h>

// Problem constants (from reference)
#define N_NODES  4096
#define EMB_DIM  512
#define N_HEADS  8
#define K_SPARSE 128
#define HEAD_DIM 64   // EMB_DIM / N_HEADS

typedef __attribute__((ext_vector_type(8))) __bf16 bf16x8;
typedef __attribute__((ext_vector_type(4))) float  f32x4;

__device__ __forceinline__ float bf2f(unsigned short u) {
    union { unsigned int i; float f; } v;
    v.i = ((unsigned int)u) << 16;
    return v.f;
}

__device__ __forceinline__ unsigned short f2bf(float f) {
    // round-to-nearest-even fp32 -> bf16
    union { float f; unsigned int i; } v;
    v.f = f;
    unsigned int x = v.i;
    unsigned int rounding = 0x7fffu + ((x >> 16) & 1u);
    x += rounding;
    return (unsigned short)(x >> 16);
}

// ---------------------------------------------------------------------------
// Kernel 1: fused Q/K projection GEMM, fp32 inputs -> bf16 outputs.
//   C[m, n] = sum_k X[m,k] * W[n,k] + bias[n]   (X @ W^T + b)
// Tile: 64x128, BK=32, 256 threads = 4 waves (2x2), each wave 32x64 via
// 2x4 grid of 16x16x32 bf16 MFMAs. Grid = 64 x 4 x 2 = 512 blocks.
// (unchanged from verified version)
// ---------------------------------------------------------------------------
__global__ __launch_bounds__(256) void proj_kernel(
    const float* __restrict__ X,
    const float* __restrict__ Wq, const float* __restrict__ bq,
    const float* __restrict__ Wk, const float* __restrict__ bk,
    unsigned short* __restrict__ Qb, unsigned short* __restrict__ Kb)
{
    __shared__ unsigned short As[64][40];    // 64 rows x 32 bf16 (+pad)
    __shared__ unsigned short Bs[128][40];   // 128 rows x 32 bf16 (+pad)

    const float* __restrict__ W    = blockIdx.z ? Wk : Wq;
    const float* __restrict__ bias = blockIdx.z ? bk : bq;
    unsigned short* __restrict__ out = blockIdx.z ? Kb : Qb;

    const int t    = threadIdx.x;
    const int M0   = blockIdx.x * 64;
    const int N0   = blockIdx.y * 128;
    const int lane = t & 63;
    const int wave = t >> 6;
    const int wm   = (wave >> 1) * 32;   // wave row offset (0 or 32)
    const int wn   = (wave & 1) * 64;    // wave col offset (0 or 64)

    const int arow = t >> 2;
    const int acol = (t & 3) * 8;
    const int brow = t >> 1;
    const int bcol = (t & 1) * 16;

    f32x4 acc[2][4] = {};

    for (int kt = 0; kt < EMB_DIM / 32; ++kt) {
        const int k0 = kt * 32;
        {
            const float4* srcA = (const float4*)(X + (size_t)(M0 + arow) * EMB_DIM + k0 + acol);
            float4 va0 = srcA[0], va1 = srcA[1];
            unsigned int pa[4];
            pa[0] = (unsigned int)f2bf(va0.x) | ((unsigned int)f2bf(va0.y) << 16);
            pa[1] = (unsigned int)f2bf(va0.z) | ((unsigned int)f2bf(va0.w) << 16);
            pa[2] = (unsigned int)f2bf(va1.x) | ((unsigned int)f2bf(va1.y) << 16);
            pa[3] = (unsigned int)f2bf(va1.z) | ((unsigned int)f2bf(va1.w) << 16);
            *(uint4*)&As[arow][acol] = make_uint4(pa[0], pa[1], pa[2], pa[3]);

            const float4* srcB = (const float4*)(W + (size_t)(N0 + brow) * EMB_DIM + k0 + bcol);
            unsigned int pb[8];
            #pragma unroll
            for (int c = 0; c < 4; ++c) {
                float4 vb = srcB[c];
                pb[c * 2 + 0] = (unsigned int)f2bf(vb.x) | ((unsigned int)f2bf(vb.y) << 16);
                pb[c * 2 + 1] = (unsigned int)f2bf(vb.z) | ((unsigned int)f2bf(vb.w) << 16);
            }
            uint4* dstB = (uint4*)&Bs[brow][bcol];
            dstB[0] = make_uint4(pb[0], pb[1], pb[2], pb[3]);
            dstB[1] = make_uint4(pb[4], pb[5], pb[6], pb[7]);
        }
        __syncthreads();

        bf16x8 af[2], bff[4];
        #pragma unroll
        for (int i = 0; i < 2; ++i)
            af[i] = __builtin_bit_cast(bf16x8,
                *(const uint4*)&As[wm + i * 16 + (lane & 15)][(lane >> 4) * 8]);
        #pragma unroll
        for (int i = 0; i < 4; ++i)
            bff[i] = __builtin_bit_cast(bf16x8,
                *(const uint4*)&Bs[wn + i * 16 + (lane & 15)][(lane >> 4) * 8]);

        #pragma unroll
        for (int mi = 0; mi < 2; ++mi)
            #pragma unroll
            for (int ni = 0; ni < 4; ++ni)
                acc[mi][ni] = __builtin_amdgcn_mfma_f32_16x16x32_bf16(
                    af[mi], bff[ni], acc[mi][ni], 0, 0, 0);
        __syncthreads();
    }

    // epilogue: +bias, fp32 -> bf16. C/D map: col=lane&15, row=(lane>>4)*4+r
    #pragma unroll
    for (int mi = 0; mi < 2; ++mi) {
        #pragma unroll
        for (int ni = 0; ni < 4; ++ni) {
            const int col = N0 + wn + ni * 16 + (lane & 15);
            const float bval = bias[col];
            #pragma unroll
            for (int r = 0; r < 4; ++r) {
                const int row = M0 + wm + mi * 16 + (lane >> 4) * 4 + r;
                out[(size_t)row * EMB_DIM + col] = f2bf(acc[mi][ni][r] + bval);
            }
        }
    }
}

// ---------------------------------------------------------------------------
// Kernel 2: one block per output row (h, n) -- R0 (best-measured) structure
// with ONE change: head <-> XCD affinity swizzle.
//
//   h = blockIdx.x & 7, n = blockIdx.x >> 3
//
// blockIdx round-robins across the 8 XCDs, so all blocks of head h land on
// XCD h. Each XCD's gather working set collapses from the whole 4 MB Kb
// table to its head's K-slices: 4096 x 128 B = 512 KB, which stays
// L2-resident. Without this, every XCD randomly gathers across all 4 MB
// while sidx/Qb/store traffic stream through the same L2 -> large HBM miss
// fraction (the round-0 189 us is ~HBM-roofline for ~1 GB of traffic).
//
// Everything else identical to the verified 559-us kernel: sectored gather
// (8 lanes/key, 16 B each), LDS atomicMax ticket dedup (last write wins),
// row staged in 16 KB LDS, nontemporal coalesced row write (NT keeps the
// K table L2-resident -- round 2 proved allocating stores cost ~130 us).
// ---------------------------------------------------------------------------
__global__ __launch_bounds__(256) void scatter_kernel(
    const unsigned short* __restrict__ Qb,
    const unsigned short* __restrict__ Kb,
    const int* __restrict__ sidx,
    float* __restrict__ out)
{
    __shared__ float rowbuf[N_NODES];
    __shared__ int   sIdx[K_SPARSE];

    const int t = threadIdx.x;
    const int b = blockIdx.x;
    const int h = b & (N_HEADS - 1);        // head = XCD (round-robin)
    const int n = b >> 3;
    const int rowid = (h << 12) | n;        // h * N_NODES + n
    const int j = t & 7;            // sector lane within key group

    // issue independent global loads first
    // Q slice: 8 bf16 (16 B) this lane needs, broadcast across each 8-lane group
    const uint4 qu = *(const uint4*)(Qb + (size_t)n * EMB_DIM + h * HEAD_DIM + j * 8);
    int myIdxLd = 0;
    if (t < K_SPARSE)
        myIdxLd = sidx[(size_t)rowid * K_SPARSE + t];

    // zero the row in LDS (256 threads x 4 f32x4 = 4096 floats)
    f32x4* rowv = (f32x4*)rowbuf;
    const f32x4 z4 = {0.0f, 0.0f, 0.0f, 0.0f};
    #pragma unroll
    for (int i = 0; i < 4; ++i) rowv[t + 256 * i] = z4;

    if (t < K_SPARSE) sIdx[t] = myIdxLd;

    // unpack this lane's 8 Q values
    float q[8];
    {
        unsigned int uu[4] = {qu.x, qu.y, qu.z, qu.w};
        #pragma unroll
        for (int w = 0; w < 4; ++w) {
            q[2 * w + 0] = bf2f((unsigned short)(uu[w] & 0xffffu));
            q[2 * w + 1] = bf2f((unsigned short)(uu[w] >> 16));
        }
    }
    __syncthreads();

    // ticket race: one thread per key (uses register idx, no LDS re-read)
    unsigned int* tags = (unsigned int*)rowbuf;
    if (t < K_SPARSE) atomicMax(&tags[myIdxLd], (unsigned int)(t + 1));

    // sectored gather + dot: key kk = (t>>3) + 32*iter, lane j covers 8 dims
    float score[4];
    int   kidx[4];
    #pragma unroll
    for (int iter = 0; iter < 4; ++iter) {
        const int kk  = (t >> 3) + 32 * iter;
        const int idx = sIdx[kk];
        kidx[iter] = idx;
        const uint4 u = *(const uint4*)(Kb + (size_t)idx * EMB_DIM + h * HEAD_DIM + j * 8);
        unsigned int uu[4] = {u.x, u.y, u.z, u.w};
        float acc = 0.0f;
        #pragma unroll
        for (int w = 0; w < 4; ++w) {
            acc += bf2f((unsigned short)(uu[w] & 0xffffu)) * q[2 * w + 0];
            acc += bf2f((unsigned short)(uu[w] >> 16))     * q[2 * w + 1];
        }
        // reduce across the 8-lane group
        acc += __shfl_xor(acc, 1);
        acc += __shfl_xor(acc, 2);
        acc += __shfl_xor(acc, 4);
        score[iter] = acc * 0.125f;   // 1/sqrt(64)
    }

    __syncthreads();   // all atomicMax tickets visible

    bool win[4];
    #pragma unroll
    for (int iter = 0; iter < 4; ++iter) {
        const int kk = (t >> 3) + 32 * iter;
        win[iter] = (j == 0) && (tags[kidx[iter]] == (unsigned int)(kk + 1));
    }

    __syncthreads();   // all tag reads done before float overwrite

    #pragma unroll
    for (int iter = 0; iter < 4; ++iter)
        if (win[iter]) rowbuf[kidx[iter]] = score[iter];

    __syncthreads();

    // coalesced nontemporal row write: 16 KB
    f32x4* orowv = (f32x4*)(out + (size_t)rowid * N_NODES);
    #pragma unroll
    for (int i = 0; i < 4; ++i)
        __builtin_nontemporal_store(rowv[t + 256 * i], &orowv[t + 256 * i]);
}

extern "C" void kernel_launch(void* const* d_in, const int* in_sizes, int n_in,
                              void* d_out, int out_size, void* d_ws, size_t ws_size,
                              hipStream_t stream) {
    const float* emb = (const float*)d_in[0];
    const float* Wq  = (const float*)d_in[1];
    const float* bq  = (const float*)d_in[2];
    const float* Wk  = (const float*)d_in[3];
    const float* bk  = (const float*)d_in[4];
    const int*   si  = (const int*)d_in[5];
    float* out = (float*)d_out;

    // workspace: Qb (4 MB) + Kb (4 MB) bf16
    unsigned short* Qb = (unsigned short*)d_ws;
    unsigned short* Kb = Qb + (size_t)N_NODES * EMB_DIM;

    dim3 pg(N_NODES / 64, EMB_DIM / 128, 2);   // 64 x 4 x 2 = 512 blocks
    proj_kernel<<<pg, 256, 0, stream>>>(emb, Wq, bq, Wk, bk, Qb, Kb);

    scatter_kernel<<<N_HEADS * N_NODES, 256, 0, stream>>>(Qb, Kb, si, out);
}